// Round 1
// baseline (475.475 us; speedup 1.0000x reference)
//
#include <hip/hip_runtime.h>
#include <math.h>

#define B 1024
#define NV 6890
#define NJ 24
#define NP 207
#define BT 16

// ---- output layout (floats) ----
// vertices: [B, NV, 3]       @ 0
// joints:   [B, 24, 3]       @ OFF_J
// j17:      [B, 17, 3]       @ OFF_J17
// rot_mats: [B, 24, 3, 3]    @ OFF_R
#define OFF_J   21166080
#define OFF_J17 21239808
#define OFF_R   21292032

// ---- workspace layout (floats) ----
#define WS_PF   0            // [B][208]  pose_feature padded to 208
#define WS_A    212992       // [B][24][12] relative transforms (3x4)
#define WS_JRX  507904       // [24*3][11]  J_regressor pre-contraction
#define WS_ROOT 508696       // [B][3]    root17

__device__ __constant__ int PAR[24] = {0,0,0,0,1,2,3,4,5,6,7,8,9,9,9,12,13,14,16,17,18,19,20,21};

// K0: JRX[(j*3+c)*11 + l] = sum_v JR[j,v] * (l==0 ? v_template[v,c] : shapedirs[v,c,l-1])
__global__ __launch_bounds__(256) void k_jrx(const float* __restrict__ JR,
    const float* __restrict__ vt, const float* __restrict__ sd,
    float* __restrict__ JRX) {
  int o = blockIdx.x;           // 0..71 = j*3+c
  int j = o / 3, c = o % 3;
  float acc[11];
#pragma unroll
  for (int q = 0; q < 11; q++) acc[q] = 0.f;
  for (int v = threadIdx.x; v < NV; v += 256) {
    float r = JR[(size_t)j * NV + v];
    acc[0] += r * vt[(size_t)v * 3 + c];
    const float* s = sd + (size_t)v * 30 + c * 10;
#pragma unroll
    for (int l = 0; l < 10; l++) acc[1 + l] += r * s[l];
  }
#pragma unroll
  for (int q = 0; q < 11; q++) {
    for (int off = 32; off; off >>= 1) acc[q] += __shfl_xor(acc[q], off, 64);
  }
  __shared__ float red[4][11];
  int wave = threadIdx.x >> 6, lane = threadIdx.x & 63;
  if (lane == 0) {
#pragma unroll
    for (int q = 0; q < 11; q++) red[wave][q] = acc[q];
  }
  __syncthreads();
  if (threadIdx.x < 11) {
    int q = threadIdx.x;
    JRX[o * 11 + q] = red[0][q] + red[1][q] + red[2][q] + red[3][q];
  }
}

// K1: per-batch rodrigues, pose_feature, joints J, kinematic chain, A, joints output
__global__ __launch_bounds__(128) void k_pose(const float* __restrict__ go,
    const float* __restrict__ paa, const float* __restrict__ betas,
    const float* __restrict__ JRX, float* __restrict__ rot_out,
    float* __restrict__ joints_out, float* __restrict__ pf, float* __restrict__ A) {
  int b = blockIdx.x, t = threadIdx.x;
  __shared__ float Rl[24][9];
  __shared__ float Jl[24][3];
  __shared__ float Cl[24][12];

  if (t < 24) {
    float x, y, z;
    if (t == 0) { x = go[b*3]; y = go[b*3+1]; z = go[b*3+2]; }
    else { const float* p = paa + (size_t)b*69 + (t-1)*3; x = p[0]; y = p[1]; z = p[2]; }
    float xe = x + 1e-8f, ye = y + 1e-8f, ze = z + 1e-8f;
    float ang = sqrtf(xe*xe + ye*ye + ze*ze);
    float inv = 1.f / ang;
    float rx = x*inv, ry = y*inv, rz = z*inv;
    float cc = cosf(ang), ss = sinf(ang), mc = 1.f - cc;
    float R[9];
    R[0]=cc+mc*rx*rx;    R[1]=mc*rx*ry-ss*rz; R[2]=mc*rx*rz+ss*ry;
    R[3]=mc*ry*rx+ss*rz; R[4]=cc+mc*ry*ry;    R[5]=mc*ry*rz-ss*rx;
    R[6]=mc*rz*rx-ss*ry; R[7]=mc*rz*ry+ss*rx; R[8]=cc+mc*rz*rz;
#pragma unroll
    for (int q = 0; q < 9; q++) {
      Rl[t][q] = R[q];
      rot_out[(size_t)b*216 + t*9 + q] = R[q];
    }
    if (t > 0) {
#pragma unroll
      for (int q = 0; q < 9; q++)
        pf[(size_t)b*208 + (t-1)*9 + q] = R[q] - ((q==0||q==4||q==8) ? 1.f : 0.f);
    }
  }
  if (t < 72) {
    int j = t / 3;
    const float* x = JRX + t * 11;
    float s = x[0];
#pragma unroll
    for (int l = 0; l < 10; l++) s += betas[(size_t)b*10 + l] * x[1 + l];
    Jl[j][t % 3] = s;
  }
  __syncthreads();
  if (t < 12) {
    int m = t >> 2, n = t & 3;
    Cl[0][t] = (n < 3) ? Rl[0][m*3+n] : Jl[0][m];
  }
  __syncthreads();
  for (int i = 1; i < 24; i++) {
    int p = PAR[i];
    if (t < 12) {
      int m = t >> 2, n = t & 3;
      float v;
      if (n < 3)
        v = Cl[p][m*4+0]*Rl[i][0*3+n] + Cl[p][m*4+1]*Rl[i][1*3+n] + Cl[p][m*4+2]*Rl[i][2*3+n];
      else {
        float r0 = Jl[i][0]-Jl[p][0], r1 = Jl[i][1]-Jl[p][1], r2 = Jl[i][2]-Jl[p][2];
        v = Cl[p][m*4+0]*r0 + Cl[p][m*4+1]*r1 + Cl[p][m*4+2]*r2 + Cl[p][m*4+3];
      }
      Cl[i][t] = v;
    }
    __syncthreads();
  }
  if (t < 72) {
    int j = t / 3, c = t % 3;
    joints_out[(size_t)b*72 + t] = Cl[j][c*4+3] - Cl[0][c*4+3];
  }
  for (int idx = t; idx < 288; idx += 128) {
    int j = idx / 12, r = idx % 12, m = r >> 2, n = r & 3;
    float v;
    if (n < 3) v = Cl[j][m*4+n];
    else v = Cl[j][m*4+3] - (Cl[j][m*4+0]*Jl[j][0] + Cl[j][m*4+1]*Jl[j][1] + Cl[j][m*4+2]*Jl[j][2]);
    A[(size_t)b*288 + idx] = v;
  }
}

// K2: the hot kernel. thread = vertex, block covers BT=16 batches.
// All batch-indexed operands (betas, pf, A) are block-uniform -> s_load + v_fma(s,v,v).
__global__ __launch_bounds__(256) void k_verts(
    const float* __restrict__ betas, const float* __restrict__ vt,
    const float* __restrict__ sd, const float* __restrict__ pd,
    const float* __restrict__ w, const float* __restrict__ pf,
    const float* __restrict__ A, float* __restrict__ verts) {
  int vraw = blockIdx.x * 256 + threadIdx.x;
  bool valid = vraw < NV;
  int v = valid ? vraw : (NV - 1);
  int b0 = blockIdx.y * BT;

  // shapedirs row (30 contiguous floats, 8B-aligned)
  float sdr[30];
  {
    const float2* s2 = (const float2*)(sd + (size_t)v * 30);
#pragma unroll
    for (int q = 0; q < 15; q++) { float2 tv = s2[q]; sdr[2*q] = tv.x; sdr[2*q+1] = tv.y; }
  }
  float vt0 = vt[(size_t)v*3+0], vt1 = vt[(size_t)v*3+1], vt2 = vt[(size_t)v*3+2];

  // v_shaped for each batch in tile
  float acc[BT][3];
#pragma unroll
  for (int i = 0; i < BT; i++) {
    const float* be = betas + (size_t)(b0 + i) * 10;
    float a0 = vt0, a1 = vt1, a2 = vt2;
#pragma unroll
    for (int l = 0; l < 10; l++) {
      float bl = be[l];
      a0 += bl * sdr[l]; a1 += bl * sdr[10+l]; a2 += bl * sdr[20+l];
    }
    acc[i][0] = a0; acc[i][1] = a1; acc[i][2] = a2;
  }

  // v_posed: += pf @ posedirs  (k-quads: 12 global loads feed 192 FMA)
  const float* pcol = pd + 3 * (size_t)v;
  for (int k = 0; k < 204; k += 4) {
    float p00,p01,p02,p10,p11,p12,p20,p21,p22,p30,p31,p32;
    { const float* r = pcol + (size_t)(k+0)*20670; p00=r[0]; p01=r[1]; p02=r[2]; }
    { const float* r = pcol + (size_t)(k+1)*20670; p10=r[0]; p11=r[1]; p12=r[2]; }
    { const float* r = pcol + (size_t)(k+2)*20670; p20=r[0]; p21=r[1]; p22=r[2]; }
    { const float* r = pcol + (size_t)(k+3)*20670; p30=r[0]; p31=r[1]; p32=r[2]; }
#pragma unroll
    for (int i = 0; i < BT; i++) {
      float4 q = *(const float4*)(pf + (size_t)(b0 + i) * 208 + k);
      acc[i][0] += q.x*p00 + q.y*p10 + q.z*p20 + q.w*p30;
      acc[i][1] += q.x*p01 + q.y*p11 + q.z*p21 + q.w*p31;
      acc[i][2] += q.x*p02 + q.y*p12 + q.z*p22 + q.w*p32;
    }
  }
  { // tail k = 204..206
    float p00,p01,p02,p10,p11,p12,p20,p21,p22;
    { const float* r = pcol + (size_t)204*20670; p00=r[0]; p01=r[1]; p02=r[2]; }
    { const float* r = pcol + (size_t)205*20670; p10=r[0]; p11=r[1]; p12=r[2]; }
    { const float* r = pcol + (size_t)206*20670; p20=r[0]; p21=r[1]; p22=r[2]; }
#pragma unroll
    for (int i = 0; i < BT; i++) {
      const float* pb = pf + (size_t)(b0 + i) * 208;
      float q0 = pb[204], q1 = pb[205], q2 = pb[206];
      acc[i][0] += q0*p00 + q1*p10 + q2*p20;
      acc[i][1] += q0*p01 + q1*p11 + q2*p21;
      acc[i][2] += q0*p02 + q1*p12 + q2*p22;
    }
  }

  // lbs weights row (24 floats, 16B-aligned)
  float wr[24];
  {
    const float4* w4 = (const float4*)(w + (size_t)v * 24);
#pragma unroll
    for (int q = 0; q < 6; q++) {
      float4 t4 = w4[q];
      wr[4*q]=t4.x; wr[4*q+1]=t4.y; wr[4*q+2]=t4.z; wr[4*q+3]=t4.w;
    }
  }

  // T = sum_j w_vj * A_bj ; verts = T[:, :3] @ v_posed + T[:,3]
#pragma unroll 1
  for (int i = 0; i < BT; i++) {
    const float* Ab = A + (size_t)(b0 + i) * 288;
    float T[12];
#pragma unroll
    for (int q = 0; q < 12; q++) T[q] = 0.f;
#pragma unroll
    for (int j = 0; j < 24; j++) {
      float wj = wr[j];
      const float4* a4 = (const float4*)(Ab + j * 12);
      float4 qa = a4[0], qb = a4[1], qc = a4[2];
      T[0]+=wj*qa.x; T[1]+=wj*qa.y; T[2]+=wj*qa.z;  T[3]+=wj*qa.w;
      T[4]+=wj*qb.x; T[5]+=wj*qb.y; T[6]+=wj*qb.z;  T[7]+=wj*qb.w;
      T[8]+=wj*qc.x; T[9]+=wj*qc.y; T[10]+=wj*qc.z; T[11]+=wj*qc.w;
    }
    float x = acc[i][0], y = acc[i][1], z = acc[i][2];
    float o0 = T[0]*x + T[1]*y + T[2]*z  + T[3];
    float o1 = T[4]*x + T[5]*y + T[6]*z  + T[7];
    float o2 = T[8]*x + T[9]*y + T[10]*z + T[11];
    if (valid) {
      float* dst = verts + ((size_t)(b0 + i) * NV + v) * 3;
      dst[0] = o0; dst[1] = o1; dst[2] = o2;
    }
  }
}

// K3: j17 = JRh @ verts per batch; write shifted j17 output + root17
__global__ __launch_bounds__(256) void k_j17(const float* __restrict__ jrh,
    const float* __restrict__ verts, float* __restrict__ j17_out,
    float* __restrict__ root) {
  int b = blockIdx.x;
  float acc[17][3];
#pragma unroll
  for (int j = 0; j < 17; j++) { acc[j][0]=0.f; acc[j][1]=0.f; acc[j][2]=0.f; }
  const float* vb = verts + (size_t)b * NV * 3;
  for (int v = threadIdx.x; v < NV; v += 256) {
    float x = vb[v*3], y = vb[v*3+1], z = vb[v*3+2];
#pragma unroll
    for (int j = 0; j < 17; j++) {
      float r = jrh[(size_t)j * NV + v];
      acc[j][0] += r*x; acc[j][1] += r*y; acc[j][2] += r*z;
    }
  }
#pragma unroll
  for (int j = 0; j < 17; j++) {
#pragma unroll
    for (int c = 0; c < 3; c++) {
      for (int off = 32; off; off >>= 1) acc[j][c] += __shfl_xor(acc[j][c], off, 64);
    }
  }
  __shared__ float red[4][51];
  __shared__ float fin[51];
  int wave = threadIdx.x >> 6, lane = threadIdx.x & 63;
  if (lane == 0) {
#pragma unroll
    for (int j = 0; j < 17; j++) {
      red[wave][j*3+0] = acc[j][0]; red[wave][j*3+1] = acc[j][1]; red[wave][j*3+2] = acc[j][2];
    }
  }
  __syncthreads();
  if (threadIdx.x < 51)
    fin[threadIdx.x] = red[0][threadIdx.x] + red[1][threadIdx.x] + red[2][threadIdx.x] + red[3][threadIdx.x];
  __syncthreads();
  if (threadIdx.x < 51) {
    int c = threadIdx.x % 3;
    j17_out[(size_t)b*51 + threadIdx.x] = fin[threadIdx.x] - fin[c];
    if (threadIdx.x < 3) root[(size_t)b*3 + threadIdx.x] = fin[threadIdx.x];
  }
}

// K4: vertices -= root17 (in place)
__global__ __launch_bounds__(256) void k_shift(float* __restrict__ verts,
    const float* __restrict__ root) {
  size_t idx = (size_t)blockIdx.x * 256 + threadIdx.x;   // over B*NV
  if (idx >= (size_t)B * NV) return;
  int b = (int)(idx / NV);
  float r0 = root[b*3], r1 = root[b*3+1], r2 = root[b*3+2];
  float* p = verts + idx * 3;
  p[0] -= r0; p[1] -= r1; p[2] -= r2;
}

extern "C" void kernel_launch(void* const* d_in, const int* in_sizes, int n_in,
                              void* d_out, int out_size, void* d_ws, size_t ws_size,
                              hipStream_t stream) {
  const float* pose  = (const float*)d_in[0];
  const float* betas = (const float*)d_in[1];
  const float* glob  = (const float*)d_in[2];
  const float* vt    = (const float*)d_in[3];
  const float* sd    = (const float*)d_in[4];
  const float* pd    = (const float*)d_in[5];
  const float* JR    = (const float*)d_in[6];
  const float* JRh   = (const float*)d_in[7];
  const float* w     = (const float*)d_in[8];
  float* out = (float*)d_out;
  float* ws  = (float*)d_ws;
  float* pf   = ws + WS_PF;
  float* A    = ws + WS_A;
  float* JRX  = ws + WS_JRX;
  float* root = ws + WS_ROOT;

  k_jrx<<<72, 256, 0, stream>>>(JR, vt, sd, JRX);
  k_pose<<<B, 128, 0, stream>>>(glob, pose, betas, JRX, out + OFF_R, out + OFF_J, pf, A);
  k_verts<<<dim3(27, B / BT), 256, 0, stream>>>(betas, vt, sd, pd, w, pf, A, out);
  k_j17<<<B, 256, 0, stream>>>(JRh, out, out + OFF_J17, root);
  k_shift<<<(B * NV + 255) / 256, 256, 0, stream>>>(out, root);
}

// Round 3
// 460.092 us; speedup vs baseline: 1.0334x; 1.0334x over previous
//
#include <hip/hip_runtime.h>
#include <math.h>

#define B 1024
#define NV 6890
#define NJ 24
#define NP 207
#define BT 16

typedef float fx2 __attribute__((ext_vector_type(2)));
typedef float fx4 __attribute__((ext_vector_type(4)));

// ---- output layout (floats) ----
#define OFF_J   21166080
#define OFF_J17 21239808
#define OFF_R   21292032

// ---- workspace layout (floats) ----
#define WS_PF   0            // [B][208]
#define WS_A    212992       // [B][24][12]
#define WS_JRX  507904       // [72][11]
#define WS_ROOT 508696       // [B][3]

__device__ __constant__ int PAR[24] = {0,0,0,0,1,2,3,4,5,6,7,8,9,9,9,12,13,14,16,17,18,19,20,21};

// K0: JRX[(j*3+c)*11 + l] = sum_v JR[j,v] * (l==0 ? v_template[v,c] : shapedirs[v,c,l-1])
__global__ __launch_bounds__(256) void k_jrx(const float* __restrict__ JR,
    const float* __restrict__ vt, const float* __restrict__ sd,
    float* __restrict__ JRX) {
  int o = blockIdx.x;           // 0..71 = j*3+c
  int j = o / 3, c = o % 3;
  float acc[11];
#pragma unroll
  for (int q = 0; q < 11; q++) acc[q] = 0.f;
  for (int v = threadIdx.x; v < NV; v += 256) {
    float r = JR[(size_t)j * NV + v];
    acc[0] += r * vt[(size_t)v * 3 + c];
    const float* s = sd + (size_t)v * 30 + c * 10;
#pragma unroll
    for (int l = 0; l < 10; l++) acc[1 + l] += r * s[l];
  }
#pragma unroll
  for (int q = 0; q < 11; q++) {
    for (int off = 32; off; off >>= 1) acc[q] += __shfl_xor(acc[q], off, 64);
  }
  __shared__ float red[4][11];
  int wave = threadIdx.x >> 6, lane = threadIdx.x & 63;
  if (lane == 0) {
#pragma unroll
    for (int q = 0; q < 11; q++) red[wave][q] = acc[q];
  }
  __syncthreads();
  if (threadIdx.x < 11) {
    int q = threadIdx.x;
    JRX[o * 11 + q] = red[0][q] + red[1][q] + red[2][q] + red[3][q];
  }
}

// K1: per-batch rodrigues, pose_feature, joints J, kinematic chain, A, joints output
__global__ __launch_bounds__(128) void k_pose(const float* __restrict__ go,
    const float* __restrict__ paa, const float* __restrict__ betas,
    const float* __restrict__ JRX, float* __restrict__ rot_out,
    float* __restrict__ joints_out, float* __restrict__ pf, float* __restrict__ A) {
  int b = blockIdx.x, t = threadIdx.x;
  __shared__ float Rl[24][9];
  __shared__ float Jl[24][3];
  __shared__ float Cl[24][12];

  if (t < 24) {
    float x, y, z;
    if (t == 0) { x = go[b*3]; y = go[b*3+1]; z = go[b*3+2]; }
    else { const float* p = paa + (size_t)b*69 + (t-1)*3; x = p[0]; y = p[1]; z = p[2]; }
    float xe = x + 1e-8f, ye = y + 1e-8f, ze = z + 1e-8f;
    float ang = sqrtf(xe*xe + ye*ye + ze*ze);
    float inv = 1.f / ang;
    float rx = x*inv, ry = y*inv, rz = z*inv;
    float cc = cosf(ang), ss = sinf(ang), mc = 1.f - cc;
    float R[9];
    R[0]=cc+mc*rx*rx;    R[1]=mc*rx*ry-ss*rz; R[2]=mc*rx*rz+ss*ry;
    R[3]=mc*ry*rx+ss*rz; R[4]=cc+mc*ry*ry;    R[5]=mc*ry*rz-ss*rx;
    R[6]=mc*rz*rx-ss*ry; R[7]=mc*rz*ry+ss*rx; R[8]=cc+mc*rz*rz;
#pragma unroll
    for (int q = 0; q < 9; q++) {
      Rl[t][q] = R[q];
      rot_out[(size_t)b*216 + t*9 + q] = R[q];
    }
    if (t > 0) {
#pragma unroll
      for (int q = 0; q < 9; q++)
        pf[(size_t)b*208 + (t-1)*9 + q] = R[q] - ((q==0||q==4||q==8) ? 1.f : 0.f);
    }
  }
  if (t < 72) {
    int j = t / 3;
    const float* x = JRX + t * 11;
    float s = x[0];
#pragma unroll
    for (int l = 0; l < 10; l++) s += betas[(size_t)b*10 + l] * x[1 + l];
    Jl[j][t % 3] = s;
  }
  __syncthreads();
  if (t < 12) {
    int m = t >> 2, n = t & 3;
    Cl[0][t] = (n < 3) ? Rl[0][m*3+n] : Jl[0][m];
  }
  __syncthreads();
  for (int i = 1; i < 24; i++) {
    int p = PAR[i];
    if (t < 12) {
      int m = t >> 2, n = t & 3;
      float v;
      if (n < 3)
        v = Cl[p][m*4+0]*Rl[i][0*3+n] + Cl[p][m*4+1]*Rl[i][1*3+n] + Cl[p][m*4+2]*Rl[i][2*3+n];
      else {
        float r0 = Jl[i][0]-Jl[p][0], r1 = Jl[i][1]-Jl[p][1], r2 = Jl[i][2]-Jl[p][2];
        v = Cl[p][m*4+0]*r0 + Cl[p][m*4+1]*r1 + Cl[p][m*4+2]*r2 + Cl[p][m*4+3];
      }
      Cl[i][t] = v;
    }
    __syncthreads();
  }
  if (t < 72) {
    int j = t / 3, c = t % 3;
    joints_out[(size_t)b*72 + t] = Cl[j][c*4+3] - Cl[0][c*4+3];
  }
  for (int idx = t; idx < 288; idx += 128) {
    int j = idx / 12, r = idx % 12, m = r >> 2, n = r & 3;
    float v;
    if (n < 3) v = Cl[j][m*4+n];
    else v = Cl[j][m*4+3] - (Cl[j][m*4+0]*Jl[j][0] + Cl[j][m*4+1]*Jl[j][1] + Cl[j][m*4+2]*Jl[j][2]);
    A[(size_t)b*288 + idx] = v;
  }
}

// K2: hot kernel. thread = vertex, block covers BT=16 batches.
// grid = (B/BT, 27): batch-tile FASTEST so consecutive blocks share the same
// posedirs vertical slice (XCD-L2 locality).
__global__ __launch_bounds__(256) void k_verts(
    const float* __restrict__ betas, const float* __restrict__ vt,
    const float* __restrict__ sd, const float* __restrict__ pd,
    const float* __restrict__ w, const float* __restrict__ pf,
    const float* __restrict__ A, float* __restrict__ verts) {
  int vbase = blockIdx.y * 256;
  int vraw = vbase + threadIdx.x;
  bool valid = vraw < NV;
  int v = valid ? vraw : (NV - 1);
  int b0 = blockIdx.x * BT;

  __shared__ float st[768];

  // shapedirs row (30 contiguous floats, 8B-aligned)
  float sdr[30];
  {
    const fx2* s2 = (const fx2*)(sd + (size_t)v * 30);
#pragma unroll
    for (int q = 0; q < 15; q++) { fx2 tv = s2[q]; sdr[2*q] = tv.x; sdr[2*q+1] = tv.y; }
  }
  float vt0 = vt[(size_t)v*3+0], vt1 = vt[(size_t)v*3+1], vt2 = vt[(size_t)v*3+2];

  // v_shaped for each batch in tile
  float acc[BT][3];
#pragma unroll
  for (int i = 0; i < BT; i++) {
    const float* be = betas + (size_t)(b0 + i) * 10;
    float a0 = vt0, a1 = vt1, a2 = vt2;
#pragma unroll
    for (int l = 0; l < 10; l++) {
      float bl = be[l];
      a0 += bl * sdr[l]; a1 += bl * sdr[10+l]; a2 += bl * sdr[20+l];
    }
    acc[i][0] = a0; acc[i][1] = a1; acc[i][2] = a2;
  }

  // v_posed: += pf @ posedirs. Register double-buffer: prefetch next k-quad.
  const float* pcol = pd + 3 * (size_t)v;
  float cur[12], nxt[12];
#pragma unroll
  for (int r = 0; r < 4; r++) {
    const float* rp = pcol + (size_t)r * 20670;
    cur[3*r] = rp[0]; cur[3*r+1] = rp[1]; cur[3*r+2] = rp[2];
  }
#pragma unroll 1
  for (int k = 0; k < 204; k += 4) {
    if (k < 200) {
#pragma unroll
      for (int r = 0; r < 4; r++) {
        const float* rp = pcol + (size_t)(k + 4 + r) * 20670;
        nxt[3*r] = rp[0]; nxt[3*r+1] = rp[1]; nxt[3*r+2] = rp[2];
      }
    }
#pragma unroll
    for (int i = 0; i < BT; i++) {
      fx4 q = *(const fx4*)(pf + (size_t)(b0 + i) * 208 + k);
      acc[i][0] += q.x*cur[0] + q.y*cur[3] + q.z*cur[6] + q.w*cur[9];
      acc[i][1] += q.x*cur[1] + q.y*cur[4] + q.z*cur[7] + q.w*cur[10];
      acc[i][2] += q.x*cur[2] + q.y*cur[5] + q.z*cur[8] + q.w*cur[11];
    }
#pragma unroll
    for (int r = 0; r < 12; r++) cur[r] = nxt[r];
  }
  { // tail k = 204..206
    float p00,p01,p02,p10,p11,p12,p20,p21,p22;
    { const float* r = pcol + (size_t)204*20670; p00=r[0]; p01=r[1]; p02=r[2]; }
    { const float* r = pcol + (size_t)205*20670; p10=r[0]; p11=r[1]; p12=r[2]; }
    { const float* r = pcol + (size_t)206*20670; p20=r[0]; p21=r[1]; p22=r[2]; }
#pragma unroll
    for (int i = 0; i < BT; i++) {
      const float* pb = pf + (size_t)(b0 + i) * 208;
      float q0 = pb[204], q1 = pb[205], q2 = pb[206];
      acc[i][0] += q0*p00 + q1*p10 + q2*p20;
      acc[i][1] += q0*p01 + q1*p11 + q2*p21;
      acc[i][2] += q0*p02 + q1*p12 + q2*p22;
    }
  }

  // lbs weights row (24 floats, 16B-aligned)
  float wr[24];
  {
    const fx4* w4 = (const fx4*)(w + (size_t)v * 24);
#pragma unroll
    for (int q = 0; q < 6; q++) {
      fx4 t4 = w4[q];
      wr[4*q]=t4.x; wr[4*q+1]=t4.y; wr[4*q+2]=t4.z; wr[4*q+3]=t4.w;
    }
  }

  int nfl = (NV - vbase) * 3; if (nfl > 768) nfl = 768;   // always even
  int nf2 = nfl >> 1;

  // T = sum_j w_vj * A_bj ; verts = T[:, :3] @ v_posed + T[:,3]
  // then LDS-repack -> contiguous fx2 nontemporal stores (full 64B lines)
#pragma unroll 1
  for (int i = 0; i < BT; i++) {
    const float* Ab = A + (size_t)(b0 + i) * 288;
    float T[12];
#pragma unroll
    for (int q = 0; q < 12; q++) T[q] = 0.f;
#pragma unroll
    for (int j = 0; j < 24; j++) {
      float wj = wr[j];
      const fx4* a4 = (const fx4*)(Ab + j * 12);
      fx4 qa = a4[0], qb = a4[1], qc = a4[2];
      T[0]+=wj*qa.x; T[1]+=wj*qa.y; T[2]+=wj*qa.z;  T[3]+=wj*qa.w;
      T[4]+=wj*qb.x; T[5]+=wj*qb.y; T[6]+=wj*qb.z;  T[7]+=wj*qb.w;
      T[8]+=wj*qc.x; T[9]+=wj*qc.y; T[10]+=wj*qc.z; T[11]+=wj*qc.w;
    }
    float x = acc[i][0], y = acc[i][1], z = acc[i][2];
    float o0 = T[0]*x + T[1]*y + T[2]*z  + T[3];
    float o1 = T[4]*x + T[5]*y + T[6]*z  + T[7];
    float o2 = T[8]*x + T[9]*y + T[10]*z + T[11];
    __syncthreads();
    st[threadIdx.x*3+0] = o0; st[threadIdx.x*3+1] = o1; st[threadIdx.x*3+2] = o2;
    __syncthreads();
    float* dst = verts + (size_t)(b0 + i) * (NV*3) + (size_t)vbase * 3;
    const fx2* s2 = (const fx2*)st;
    int q = threadIdx.x;
    if (q < nf2) __builtin_nontemporal_store(s2[q], (fx2*)dst + q);
    q += 256;
    if (q < nf2) __builtin_nontemporal_store(s2[q], (fx2*)dst + q);
  }
}

// K3: j17 = JRh @ verts per batch; write shifted j17 output + root17
__global__ __launch_bounds__(256) void k_j17(const float* __restrict__ jrh,
    const float* __restrict__ verts, float* __restrict__ j17_out,
    float* __restrict__ root) {
  int b = blockIdx.x;
  float acc[17][3];
#pragma unroll
  for (int j = 0; j < 17; j++) { acc[j][0]=0.f; acc[j][1]=0.f; acc[j][2]=0.f; }
  const float* vb = verts + (size_t)b * NV * 3;
  for (int v = threadIdx.x; v < NV; v += 256) {
    float x = vb[v*3], y = vb[v*3+1], z = vb[v*3+2];
#pragma unroll
    for (int j = 0; j < 17; j++) {
      float r = jrh[(size_t)j * NV + v];
      acc[j][0] += r*x; acc[j][1] += r*y; acc[j][2] += r*z;
    }
  }
#pragma unroll
  for (int j = 0; j < 17; j++) {
#pragma unroll
    for (int c = 0; c < 3; c++) {
      for (int off = 32; off; off >>= 1) acc[j][c] += __shfl_xor(acc[j][c], off, 64);
    }
  }
  __shared__ float red[4][51];
  __shared__ float fin[51];
  int wave = threadIdx.x >> 6, lane = threadIdx.x & 63;
  if (lane == 0) {
#pragma unroll
    for (int j = 0; j < 17; j++) {
      red[wave][j*3+0] = acc[j][0]; red[wave][j*3+1] = acc[j][1]; red[wave][j*3+2] = acc[j][2];
    }
  }
  __syncthreads();
  if (threadIdx.x < 51)
    fin[threadIdx.x] = red[0][threadIdx.x] + red[1][threadIdx.x] + red[2][threadIdx.x] + red[3][threadIdx.x];
  __syncthreads();
  if (threadIdx.x < 51) {
    int c = threadIdx.x % 3;
    j17_out[(size_t)b*51 + threadIdx.x] = fin[threadIdx.x] - fin[c];
    if (threadIdx.x < 3) root[(size_t)b*3 + threadIdx.x] = fin[threadIdx.x];
  }
}

// K4: vertices -= root17 (in place), fx4 per thread.
// 21,166,080 floats = 5,291,520 float4 exactly; 20670 % 3 == 0 so c = f % 3.
__global__ __launch_bounds__(256) void k_shift(float* __restrict__ verts,
    const float* __restrict__ root) {
  int t = blockIdx.x * 256 + threadIdx.x;       // < 5291520
  fx4 x = ((const fx4*)verts)[t];
  int f0 = t * 4;
  int b  = f0 / 20670;
  int r  = f0 - b * 20670;
  int c0 = f0 % 3;
  int c1 = c0 + 1; if (c1 == 3) c1 = 0;
  int c2 = c1 + 1; if (c2 == 3) c2 = 0;
  int c3 = c0;
  float r0x = root[b*3+0], r0y = root[b*3+1], r0z = root[b*3+2];
  if (r < 20667) {                               // fast path: no batch crossing
    const float rr[3] = {r0x, r0y, r0z};
    x.x -= rr[c0]; x.y -= rr[c1]; x.z -= rr[c2]; x.w -= rr[c3];
  } else {
    int b1 = b + 1; if (b1 > B-1) b1 = B-1;
    const float rr0[3] = {r0x, r0y, r0z};
    const float rr1[3] = {root[b1*3+0], root[b1*3+1], root[b1*3+2]};
    x.x -= (r+0 >= 20670 ? rr1 : rr0)[c0];
    x.y -= (r+1 >= 20670 ? rr1 : rr0)[c1];
    x.z -= (r+2 >= 20670 ? rr1 : rr0)[c2];
    x.w -= (r+3 >= 20670 ? rr1 : rr0)[c3];
  }
  __builtin_nontemporal_store(x, (fx4*)verts + t);
}

extern "C" void kernel_launch(void* const* d_in, const int* in_sizes, int n_in,
                              void* d_out, int out_size, void* d_ws, size_t ws_size,
                              hipStream_t stream) {
  const float* pose  = (const float*)d_in[0];
  const float* betas = (const float*)d_in[1];
  const float* glob  = (const float*)d_in[2];
  const float* vt    = (const float*)d_in[3];
  const float* sd    = (const float*)d_in[4];
  const float* pd    = (const float*)d_in[5];
  const float* JR    = (const float*)d_in[6];
  const float* JRh   = (const float*)d_in[7];
  const float* w     = (const float*)d_in[8];
  float* out = (float*)d_out;
  float* ws  = (float*)d_ws;
  float* pf   = ws + WS_PF;
  float* A    = ws + WS_A;
  float* JRX  = ws + WS_JRX;
  float* root = ws + WS_ROOT;

  k_jrx<<<72, 256, 0, stream>>>(JR, vt, sd, JRX);
  k_pose<<<B, 128, 0, stream>>>(glob, pose, betas, JRX, out + OFF_R, out + OFF_J, pf, A);
  k_verts<<<dim3(B / BT, 27), 256, 0, stream>>>(betas, vt, sd, pd, w, pf, A, out);
  k_j17<<<B, 256, 0, stream>>>(JRh, out, out + OFF_J17, root);
  k_shift<<<(B * NV * 3) / 4 / 256, 256, 0, stream>>>(out, root);
}